// Round 8
// baseline (42.028 us; speedup 1.0000x reference)
//
#include <hip/hip_runtime.h>

#define NB 2
#define NCK 8                    // tracked components 1..8 (comp 0 dropped)
#define NVAL (NCK * 2)           // {inter,count} x 8 per batch
#define NBINS (NB * NVAL)        // 32 global bins
#define SMOOTHF 1e-5f

// Bin-major LDS: bins[c][tid] (float2 {inter,count}).
// addr(float) = c*512 + tid*2 + part -> bank = (2*lane + part) % 32,
// independent of the data-dependent component c (512 % 32 == 0) and of the
// wave id (128 % 32 == 0). 2-way b64 alias only (free, m136).
__global__ __launch_bounds__(256) void cc_accum(
        const float* __restrict__ y_pred,
        const int* __restrict__ y,
        const int* __restrict__ comp,
        float* __restrict__ partial,   // [NBINS][nblk], column = global blockIdx
        int* __restrict__ ticket,
        int V4, int BPB, int nblk) {
    __shared__ __align__(8) float2 bins[9][256];
    __shared__ float redbuf[16 * 17];   // [vv][q], row stride 17 (final-stage spread)

    #pragma unroll
    for (int i = 0; i < 9; ++i) bins[i][threadIdx.x] = make_float2(0.0f, 0.0f);
    if (blockIdx.x == 0 && threadIdx.x == 0) *ticket = 0;   // stream-ordered init
    // no barrier: each thread touches only its own column until drain

    const int b   = (blockIdx.x >= BPB) ? 1 : 0;   // batch is block-uniform
    const int blk = blockIdx.x - b * BPB;
    const int stride = BPB * 256;

    const float* p0 = y_pred + (size_t)b * 2 * ((size_t)V4 * 4);
    const float* p1 = p0 + (size_t)V4 * 4;
    const int4* yq = (const int4*)y    + (size_t)b * V4;
    const int4* cq = (const int4*)comp + (size_t)b * V4;

    for (int v = blk * 256 + threadIdx.x; v < V4; v += stride) {
        const float4 a0 = ((const float4*)p0)[v];
        const float4 a1 = ((const float4*)p1)[v];
        const int4 t = yq[v];
        const int4 c = cq[v];

        // p_true = softmax(y_pred)[true] = 1/(1+exp(t ? a0-a1 : a1-a0))
        {
            const float d = a0.x - a1.x;
            const float p = 1.0f / (1.0f + __expf(t.x ? d : -d));
            float2 s = bins[c.x][threadIdx.x]; s.x += p; s.y += 1.0f; bins[c.x][threadIdx.x] = s;
        }
        {
            const float d = a0.y - a1.y;
            const float p = 1.0f / (1.0f + __expf(t.y ? d : -d));
            float2 s = bins[c.y][threadIdx.x]; s.x += p; s.y += 1.0f; bins[c.y][threadIdx.x] = s;
        }
        {
            const float d = a0.z - a1.z;
            const float p = 1.0f / (1.0f + __expf(t.z ? d : -d));
            float2 s = bins[c.z][threadIdx.x]; s.x += p; s.y += 1.0f; bins[c.z][threadIdx.x] = s;
        }
        {
            const float d = a0.w - a1.w;
            const float p = 1.0f / (1.0f + __expf(t.w ? d : -d));
            float2 s = bins[c.w][threadIdx.x]; s.x += p; s.y += 1.0f; bins[c.w][threadIdx.x] = s;
        }
    }
    __syncthreads();

    // Drain: value vv = tid>>4 (= 2*(comp-1)+part), chunk q = tid&15 sums
    // columns q+16k. bank = (2q+part)%32 -> thread-determined, conflict-free.
    {
        const int vv = threadIdx.x >> 4, q = threadIdx.x & 15;
        const int c  = (vv >> 1) + 1, part = vv & 1;
        const float* base = (const float*)&bins[c][0];
        float s = 0.0f;
        #pragma unroll
        for (int k = 0; k < 16; ++k)
            s += base[(q + 16 * k) * 2 + part];
        redbuf[vv * 17 + q] = s;
    }
    __syncthreads();
    if (threadIdx.x < NVAL) {
        const int j = threadIdx.x;
        float s = 0.0f;
        #pragma unroll
        for (int q = 0; q < 16; ++q) s += redbuf[j * 17 + q];
        partial[(size_t)(b * NVAL + j) * nblk + blockIdx.x] = s;
    }
}

// Reduce + fused final via last-block ticket. All cross-block data goes
// through device-scope atomics + __threadfence (G12/G16).
__global__ __launch_bounds__(256) void cc_reduce(
        const float* __restrict__ partial, float* __restrict__ fin,
        int* __restrict__ ticket, float* __restrict__ out,
        int half, int nblk) {
    const int bin = blockIdx.x;            // 0..NBINS-1
    const int b = (bin >= NVAL) ? 1 : 0;   // which batch's columns hold data
    const int c0 = b * half;
    float s = 0.0f;
    for (int i = threadIdx.x; i < half; i += 256)
        s += partial[(size_t)bin * nblk + c0 + i];
    #pragma unroll
    for (int off = 32; off; off >>= 1) s += __shfl_xor(s, off);
    __shared__ float w4[4];
    if ((threadIdx.x & 63) == 0) w4[threadIdx.x >> 6] = s;
    __syncthreads();
    if (threadIdx.x == 0) {
        const float tot = w4[0] + w4[1] + w4[2] + w4[3];
        atomicExch(&fin[bin], tot);        // coherent publish
        __threadfence();                   // release
        const int old = atomicAdd(ticket, 1);
        if (old == NBINS - 1) {            // last block finalizes
            __threadfence();               // acquire
            float v[NBINS];
            #pragma unroll
            for (int i = 0; i < NBINS; ++i)
                v[i] = atomicAdd(&fin[i], 0.0f);   // coherent read
            // psum = tsum = count (softmax over 2 ch sums to 1; one-hot sums to 1)
            float total = 0.0f;
            for (int bb = 0; bb < NB; ++bb) {
                float dsum = 0.0f, pc = 0.0f;
                for (int j = 0; j < NCK; ++j) {
                    const float inter = v[bb * NVAL + 2 * j];
                    const float cnt   = v[bb * NVAL + 2 * j + 1];
                    if (cnt > 0.0f) {
                        dsum += 1.0f - (2.0f * inter + SMOOTHF) / (2.0f * cnt + SMOOTHF);
                        pc += 1.0f;
                    }
                }
                total += dsum / fmaxf(pc, 1.0f);
            }
            out[0] = total / (float)NB;
        }
    }
}

extern "C" void kernel_launch(void* const* d_in, const int* in_sizes, int n_in,
                              void* d_out, int out_size, void* d_ws, size_t ws_size,
                              hipStream_t stream) {
    const float* y_pred = (const float*)d_in[0];
    const int*   y      = (const int*)d_in[1];
    const int*   comp   = (const int*)d_in[2];
    float* out = (float*)d_out;
    float* ws  = (float*)d_ws;

    const int nvox = in_sizes[1];    // B * V = 8,192,000
    const int V    = nvox / NB;      // 4,096,000
    const int V4   = V / 4;          // 1,024,000 quads per batch

    int BPB = 1024;                  // blocks per batch -> 2048 total = 8/CU
    int cap_rows = (int)((ws_size / sizeof(float) - NBINS - 4) / NBINS);
    if (2 * BPB > cap_rows) BPB = cap_rows / 2;
    if (BPB > V4) BPB = V4;
    if (BPB < 1) BPB = 1;
    const int nblk = 2 * BPB;

    float* fin    = ws + (size_t)NBINS * nblk;
    int*   ticket = (int*)(fin + NBINS);

    cc_accum<<<dim3(nblk), dim3(256), 0, stream>>>(y_pred, y, comp, ws, ticket, V4, BPB, nblk);
    cc_reduce<<<dim3(NBINS), dim3(256), 0, stream>>>(ws, fin, ticket, out, BPB, nblk);
}

// Round 9
// 32.979 us; speedup vs baseline: 1.2744x; 1.2744x over previous
//
#include <hip/hip_runtime.h>

#define NB 2
#define NCK 8                    // tracked components 1..8 (comp 0 dropped)
#define NVAL (NCK * 2)           // {inter,count} x 8 per batch
#define NSL 32                   // 32 values: b0[16] | b1[16]
#define NREP 64                  // replica count for contention-free global atomics
#define SMOOTHF 1e-5f

__global__ __launch_bounds__(512) void cc_zero(float* __restrict__ rep) {
    ((float4*)rep)[threadIdx.x] = make_float4(0.f, 0.f, 0.f, 0.f);  // 512*16B = 8KB
}

// Bin-major LDS: bins[c][tid] (float2 {inter,count}).
// addr(float) = c*512 + tid*2 + part -> bank = (2*lane + part) % 32,
// independent of the data-dependent component c (512 % 32 == 0). Proven:
// SQ_LDS_BANK_CONFLICT 2.1M -> 16K (R8).
__global__ __launch_bounds__(256) void cc_accum(
        const float* __restrict__ y_pred,
        const int* __restrict__ y,
        const int* __restrict__ comp,
        float* __restrict__ rep,       // [NREP][NSL] replicated bins
        int V4, int BPB) {
    __shared__ __align__(8) float2 bins[9][256];
    __shared__ float redbuf[16 * 17];   // [vv][q], stride 17

    #pragma unroll
    for (int i = 0; i < 9; ++i) bins[i][threadIdx.x] = make_float2(0.0f, 0.0f);
    // no barrier: each thread touches only its own column until drain

    const int b   = (blockIdx.x >= BPB) ? 1 : 0;   // batch is block-uniform
    const int blk = blockIdx.x - b * BPB;
    const int stride = BPB * 256;

    const float* p0 = y_pred + (size_t)b * 2 * ((size_t)V4 * 4);
    const float* p1 = p0 + (size_t)V4 * 4;
    const int4* yq = (const int4*)y    + (size_t)b * V4;
    const int4* cq = (const int4*)comp + (size_t)b * V4;

    for (int v = blk * 256 + threadIdx.x; v < V4; v += stride) {
        const float4 a0 = ((const float4*)p0)[v];
        const float4 a1 = ((const float4*)p1)[v];
        const int4 t = yq[v];
        const int4 c = cq[v];

        // p_true = softmax(y_pred)[true] = 1/(1+exp(t ? a0-a1 : a1-a0))
        {
            const float d = a0.x - a1.x;
            const float p = 1.0f / (1.0f + __expf(t.x ? d : -d));
            float2 s = bins[c.x][threadIdx.x]; s.x += p; s.y += 1.0f; bins[c.x][threadIdx.x] = s;
        }
        {
            const float d = a0.y - a1.y;
            const float p = 1.0f / (1.0f + __expf(t.y ? d : -d));
            float2 s = bins[c.y][threadIdx.x]; s.x += p; s.y += 1.0f; bins[c.y][threadIdx.x] = s;
        }
        {
            const float d = a0.z - a1.z;
            const float p = 1.0f / (1.0f + __expf(t.z ? d : -d));
            float2 s = bins[c.z][threadIdx.x]; s.x += p; s.y += 1.0f; bins[c.z][threadIdx.x] = s;
        }
        {
            const float d = a0.w - a1.w;
            const float p = 1.0f / (1.0f + __expf(t.w ? d : -d));
            float2 s = bins[c.w][threadIdx.x]; s.x += p; s.y += 1.0f; bins[c.w][threadIdx.x] = s;
        }
    }
    __syncthreads();

    // Drain: value vv = tid>>4 (= 2*(comp-1)+part), chunk q = tid&15 sums
    // columns q+16k. bank = (2q+part)%32 -> thread-determined, conflict-free.
    {
        const int vv = threadIdx.x >> 4, q = threadIdx.x & 15;
        const int c  = (vv >> 1) + 1, part = vv & 1;
        const float* base = (const float*)&bins[c][0];
        float s = 0.0f;
        #pragma unroll
        for (int k = 0; k < 16; ++k)
            s += base[(q + 16 * k) * 2 + part];
        redbuf[vv * 17 + q] = s;
    }
    __syncthreads();
    // 16 global atomics per block into this block's replica slot: <=16
    // colliders per address, spread over block completion times.
    if (threadIdx.x < NVAL) {
        const int j = threadIdx.x;
        float s = 0.0f;
        #pragma unroll
        for (int q = 0; q < 16; ++q) s += redbuf[j * 17 + q];
        atomicAdd(&rep[(size_t)(blockIdx.x & (NREP - 1)) * NSL + b * NVAL + j], s);
    }
}

// Final: one block reads the 8 KB replica array, reduces NREP->1, epilogue.
__global__ __launch_bounds__(256) void cc_final(
        const float* __restrict__ rep, float* __restrict__ out) {
    const int tid = threadIdx.x;
    const int j = tid & 31, g = tid >> 5;       // 8 groups x 32 values
    float s = 0.0f;
    #pragma unroll
    for (int k = 0; k < NREP / 8; ++k)          // each group sums 8 replicas
        s += rep[(size_t)(g * (NREP / 8) + k) * NSL + j];

    __shared__ float red[8][NSL];
    red[g][j] = s;
    __syncthreads();
    __shared__ float fin[NSL];
    if (tid < NSL) {
        float t = 0.0f;
        #pragma unroll
        for (int gg = 0; gg < 8; ++gg) t += red[gg][tid];
        fin[tid] = t;
    }
    __syncthreads();
    if (tid == 0) {
        // psum = tsum = count (softmax over 2 ch sums to 1; one-hot sums to 1)
        float total = 0.0f;
        for (int b = 0; b < NB; ++b) {
            float dsum = 0.0f, pc = 0.0f;
            for (int jj = 0; jj < NCK; ++jj) {
                const float inter = fin[b * NVAL + 2 * jj];
                const float cnt   = fin[b * NVAL + 2 * jj + 1];
                if (cnt > 0.0f) {
                    dsum += 1.0f - (2.0f * inter + SMOOTHF) / (2.0f * cnt + SMOOTHF);
                    pc += 1.0f;
                }
            }
            total += dsum / fmaxf(pc, 1.0f);
        }
        out[0] = total / (float)NB;
    }
}

extern "C" void kernel_launch(void* const* d_in, const int* in_sizes, int n_in,
                              void* d_out, int out_size, void* d_ws, size_t ws_size,
                              hipStream_t stream) {
    const float* y_pred = (const float*)d_in[0];
    const int*   y      = (const int*)d_in[1];
    const int*   comp   = (const int*)d_in[2];
    float* out = (float*)d_out;
    float* rep = (float*)d_ws;       // NREP*NSL = 2048 floats = 8 KB

    const int nvox = in_sizes[1];    // B * V = 8,192,000
    const int V    = nvox / NB;      // 4,096,000
    const int V4   = V / 4;          // 1,024,000 quads per batch

    int BPB = 1024;                  // blocks per batch -> 2048 total = 8/CU
    if (BPB > V4) BPB = V4;
    if (BPB < 1) BPB = 1;
    const int nblk = 2 * BPB;

    cc_zero <<<dim3(1),    dim3(512), 0, stream>>>(rep);
    cc_accum<<<dim3(nblk), dim3(256), 0, stream>>>(y_pred, y, comp, rep, V4, BPB);
    cc_final<<<dim3(1),    dim3(256), 0, stream>>>(rep, out);
}